// Round 7
// baseline (74.015 us; speedup 1.0000x reference)
//
#include <hip/hip_runtime.h>

#define BB 8
#define TT 24
#define NN 4096   // C*C
#define HH 32
#define JT 64     // j-tile width
#define UPB (TT*HH) // 768
#define CTRS 16   // counter stride (words) — one cacheline-ish per counter

// ---------------- K1: norm (192 blocks) + z0raw = Edge@W0 (512 blocks) ----------------
// Also zeroes u accumulators and the barrier counters.
__global__ __launch_bounds__(256) void k_phase1(const float* __restrict__ Flow,
                                                const float* __restrict__ Edge,
                                                const float* __restrict__ W0,
                                                float* __restrict__ rn,
                                                float* __restrict__ s,
                                                float* __restrict__ uz /* u + ctr zero region */,
                                                float* __restrict__ z0raw) {
    const int blk = blockIdx.x;
    const int tid = threadIdx.x;

    if (blk < BB * TT) {
        const float4* x = (const float4*)(Flow + (size_t)blk * NN);
        float sq = 0.f, sm = 0.f;
#pragma unroll
        for (int i = 0; i < 4; ++i) {
            float4 v = x[tid + i * 256];
            sq += v.x * v.x + v.y * v.y + v.z * v.z + v.w * v.w;
            sm += v.x + v.y + v.z + v.w;
        }
#pragma unroll
        for (int off = 32; off > 0; off >>= 1) {
            sq += __shfl_down(sq, off);
            sm += __shfl_down(sm, off);
        }
        __shared__ float rss[4], rsm[4];
        int wave = tid >> 6, lane = tid & 63;
        if (lane == 0) { rss[wave] = sq; rsm[wave] = sm; }
        __syncthreads();
        if (tid == 0) {
            float tss = rss[0] + rss[1] + rss[2] + rss[3];
            float tsm = rsm[0] + rsm[1] + rsm[2] + rsm[3];
            float r = 1.0f / fmaxf(sqrtf(tss), 1e-12f);
            rn[blk] = r;
            s[blk] = tsm * r;
        }
        // zero u (18432 floats) + counters (384 words) = 18816
        int gid = blk * 256 + tid;
        if (gid < 3 * BB * TT * HH + 3 * BB * CTRS) uz[gid] = 0.f;
    } else {
        const int g = blk - BB * TT;
        const int b = g >> 6;
        const int j0 = (g & 63) * JT;

        __shared__ float xs[JT][33];
        __shared__ float Ws[32][32];
        for (int i = tid; i < 1024; i += 256) Ws[i >> 5][i & 31] = W0[i];
        {
            const float4* eb = (const float4*)(Edge + ((size_t)b * NN + j0) * HH);
#pragma unroll
            for (int k = 0; k < 2; ++k) {
                int i = tid + k * 256;
                float4 v = eb[i];
                int r0 = i >> 3, c0 = (i & 7) * 4;
                xs[r0][c0] = v.x; xs[r0][c0 + 1] = v.y; xs[r0][c0 + 2] = v.z; xs[r0][c0 + 3] = v.w;
            }
        }
        __syncthreads();
        const int r = tid >> 2;
        const int h0 = (tid & 3) * 8;
        float zr[8];
#pragma unroll
        for (int hh = 0; hh < 8; ++hh) {
            float acc = 0.f;
#pragma unroll
            for (int e = 0; e < 32; ++e) acc += xs[r][e] * Ws[e][h0 + hh];
            zr[hh] = acc;
        }
        float* zb = z0raw + ((size_t)b * NN + j0 + r) * HH + h0;
        ((float4*)zb)[0] = make_float4(zr[0], zr[1], zr[2], zr[3]);
        ((float4*)zb)[1] = make_float4(zr[4], zr[5], zr[6], zr[7]);
    }
}

// ---------------- K2: persistent 3-layer kernel with per-batch barriers ----------------
__global__ __launch_bounds__(256) void k_mega(const float* __restrict__ Flow,
                                              const float* __restrict__ z0raw,
                                              const float* __restrict__ rn,
                                              const float* __restrict__ s,
                                              const float* __restrict__ W1,
                                              const float* __restrict__ W2,
                                              const float* __restrict__ b0,
                                              const float* __restrict__ b1,
                                              const float* __restrict__ b2,
                                              float* __restrict__ u,
                                              unsigned* __restrict__ ctr,
                                              float* __restrict__ out) {
    const int blk = blockIdx.x;
    const int b = blk >> 6;               // batch-contiguous -> deadlock-free
    const int j0 = (blk & 63) * JT;
    const int tid = threadIdx.x;

    __shared__ float xns[TT][JT];
    __shared__ float zs[JT][33];
    __shared__ float xs[JT][33];
    __shared__ float W1s[32][32];
    __shared__ float W2s[32][32];
    __shared__ float us[TT][32];
    __shared__ float sS[TT];
    __shared__ float b0s[32], b1s[32], b2s[32];

    // ---- stage persistent block state ----
    if (tid < TT) sS[tid] = s[b * TT + tid];
    if (tid < 32) { b0s[tid] = b0[tid]; b1s[tid] = b1[tid]; b2s[tid] = b2[tid]; }
    for (int i = tid; i < 1024; i += 256) { W1s[i >> 5][i & 31] = W1[i]; W2s[i >> 5][i & 31] = W2[i]; }
    {
        const float4* zt = (const float4*)(z0raw + ((size_t)b * NN + j0) * HH);
#pragma unroll
        for (int k = 0; k < 2; ++k) {
            int i = tid + k * 256;
            float4 v = zt[i];
            int r0 = i >> 3, c0 = (i & 7) * 4;
            zs[r0][c0] = v.x; zs[r0][c0 + 1] = v.y; zs[r0][c0 + 2] = v.z; zs[r0][c0 + 3] = v.w;
        }
    }
    {
        const float* flb = Flow + (size_t)b * TT * NN + j0;
        for (int i = tid; i < TT * (JT / 4); i += 256) {
            int t = i >> 4, c0 = (i & 15) * 4;
            float4 v = ((const float4*)(flb + t * NN))[i & 15];
            float rt = rn[b * TT + t];
            xns[t][c0] = v.x * rt; xns[t][c0 + 1] = v.y * rt;
            xns[t][c0 + 2] = v.z * rt; xns[t][c0 + 3] = v.w * rt;
        }
    }
    __syncthreads();

    const int r = tid >> 2;
    const int h0 = (tid & 3) * 8;
    float deg = 1.0f;
#pragma unroll
    for (int t = 0; t < TT; ++t) deg += xns[t][r] * sS[t];
    const float di = (deg > 0.f) ? rsqrtf(deg) : 0.f;
#pragma unroll
    for (int hh = 0; hh < 8; ++hh) zs[r][h0 + hh] *= di;   // zs = di * z0raw
    __syncthreads();

    float* u0 = u + b * UPB;
    float* u1 = u0 + BB * UPB;
    float* u2 = u1 + BB * UPB;

#define U_PART(dst)                                                        \
    {                                                                      \
        _Pragma("unroll")                                                  \
        for (int k = 0; k < 3; ++k) {                                      \
            int p = tid + k * 256;                                         \
            int t = p >> 5, h = p & 31;                                    \
            float acc = 0.f;                                               \
            _Pragma("unroll 8")                                            \
            for (int rr = 0; rr < JT; ++rr) acc += xns[t][rr] * zs[rr][h]; \
            atomicAdd(&(dst)[t * HH + h], acc);                            \
        }                                                                  \
    }

#define BAR(phase)                                                                  \
    {                                                                               \
        __syncthreads(); /* drains vmcnt -> this block's atomics performed */       \
        if (tid == 0) {                                                             \
            unsigned* c = ctr + ((phase) * BB + b) * CTRS;                          \
            __hip_atomic_fetch_add(c, 1u, __ATOMIC_RELEASE, __HIP_MEMORY_SCOPE_AGENT); \
            while (__hip_atomic_load(c, __ATOMIC_ACQUIRE, __HIP_MEMORY_SCOPE_AGENT) < 64u) \
                __builtin_amdgcn_s_sleep(2);                                        \
        }                                                                           \
        __syncthreads();                                                            \
    }

#define LOAD_US(src)                                                                \
    {                                                                               \
        _Pragma("unroll")                                                           \
        for (int k = 0; k < 3; ++k) {                                               \
            int p = tid + k * 256;                                                  \
            us[p >> 5][p & 31] = __hip_atomic_load(&(src)[p], __ATOMIC_RELAXED,     \
                                                   __HIP_MEMORY_SCOPE_AGENT);       \
        }                                                                           \
        __syncthreads();                                                            \
    }

    // ---- layer 0 reduction ----
    U_PART(u0);
    BAR(0);
    LOAD_US(u0);

    // ---- layer 1 ----
#pragma unroll
    for (int hh = 0; hh < 8; ++hh) {
        int h = h0 + hh;
        float acc = 0.f;
#pragma unroll
        for (int t = 0; t < TT; ++t) acc += xns[t][r] * us[t][h];
        xs[r][h] = fmaxf(di * (acc + zs[r][h]) + b0s[h], 0.f);
    }
    // threads 4r..4r+3 (same wave64) wrote xs[r][0..31]: program-order LDS
    // visibility within a wave (validated R1/R2/R4/R5)
#pragma unroll
    for (int hh = 0; hh < 8; ++hh) {
        float acc = 0.f;
#pragma unroll
        for (int e = 0; e < 32; ++e) acc += xs[r][e] * W1s[e][h0 + hh];
        zs[r][h0 + hh] = di * acc;
    }
    __syncthreads();
    U_PART(u1);
    BAR(1);
    LOAD_US(u1);

    // ---- layer 2 ----
#pragma unroll
    for (int hh = 0; hh < 8; ++hh) {
        int h = h0 + hh;
        float acc = 0.f;
#pragma unroll
        for (int t = 0; t < TT; ++t) acc += xns[t][r] * us[t][h];
        xs[r][h] = fmaxf(di * (acc + zs[r][h]) + b1s[h], 0.f);
    }
#pragma unroll
    for (int hh = 0; hh < 8; ++hh) {
        float acc = 0.f;
#pragma unroll
        for (int e = 0; e < 32; ++e) acc += xs[r][e] * W2s[e][h0 + hh];
        zs[r][h0 + hh] = di * acc;
    }
    __syncthreads();
    U_PART(u2);
    BAR(2);
    LOAD_US(u2);

    // ---- final B -> out ----
    float o[8];
#pragma unroll
    for (int hh = 0; hh < 8; ++hh) {
        int h = h0 + hh;
        float acc = 0.f;
#pragma unroll
        for (int t = 0; t < TT; ++t) acc += xns[t][r] * us[t][h];
        o[hh] = fmaxf(di * (acc + zs[r][h]) + b2s[h], 0.f);
    }
    float* orow = out + ((size_t)b * NN + j0 + r) * HH + h0;
    ((float4*)orow)[0] = make_float4(o[0], o[1], o[2], o[3]);
    ((float4*)orow)[1] = make_float4(o[4], o[5], o[6], o[7]);

#undef U_PART
#undef BAR
#undef LOAD_US
}

extern "C" void kernel_launch(void* const* d_in, const int* in_sizes, int n_in,
                              void* d_out, int out_size, void* d_ws, size_t ws_size,
                              hipStream_t stream) {
    const float* Flow = (const float*)d_in[0];
    const float* Edge = (const float*)d_in[1];
    const float* W0 = (const float*)d_in[2];
    const float* b0 = (const float*)d_in[3];
    const float* W1 = (const float*)d_in[4];
    const float* b1 = (const float*)d_in[5];
    const float* W2 = (const float*)d_in[6];
    const float* b2 = (const float*)d_in[7];
    float* out = (float*)d_out;

    float* ws = (float*)d_ws;
    float* rn    = ws;                                  // B*T
    float* s     = rn + BB * TT;                        // B*T
    float* z0raw = s + BB * TT;                         // B*N*H
    float* u     = z0raw + (size_t)BB * NN * HH;        // 3*B*T*H
    unsigned* ctr = (unsigned*)(u + 3 * BB * UPB);      // 3*B*CTRS words

    k_phase1<<<dim3(BB * TT + 512), 256, 0, stream>>>(Flow, Edge, W0, rn, s, u, z0raw);
    k_mega<<<dim3(512), 256, 0, stream>>>(Flow, z0raw, rn, s, W1, W2, b0, b1, b2,
                                          u, ctr, out);
}

// Round 8
// 46.551 us; speedup vs baseline: 1.5900x; 1.5900x over previous
//
#include <hip/hip_runtime.h>

#define BB 8
#define TT 24
#define NN 4096   // C*C
#define HH 32
#define JT 64     // j-tile width
#define UPB (TT*HH) // 768
#define CTRS 16   // counter stride (words)

// ---------------- K1: norm (192 blocks) + z0raw = Edge@W0 (512 blocks) ----------------
// Also zeroes u accumulators and the barrier counters (flushed at kernel end).
__global__ __launch_bounds__(256) void k_phase1(const float* __restrict__ Flow,
                                                const float* __restrict__ Edge,
                                                const float* __restrict__ W0,
                                                float* __restrict__ rn,
                                                float* __restrict__ s,
                                                float* __restrict__ uz /* u + ctr zero region */,
                                                float* __restrict__ z0raw) {
    const int blk = blockIdx.x;
    const int tid = threadIdx.x;

    if (blk < BB * TT) {
        const float4* x = (const float4*)(Flow + (size_t)blk * NN);
        float sq = 0.f, sm = 0.f;
#pragma unroll
        for (int i = 0; i < 4; ++i) {
            float4 v = x[tid + i * 256];
            sq += v.x * v.x + v.y * v.y + v.z * v.z + v.w * v.w;
            sm += v.x + v.y + v.z + v.w;
        }
#pragma unroll
        for (int off = 32; off > 0; off >>= 1) {
            sq += __shfl_down(sq, off);
            sm += __shfl_down(sm, off);
        }
        __shared__ float rss[4], rsm[4];
        int wave = tid >> 6, lane = tid & 63;
        if (lane == 0) { rss[wave] = sq; rsm[wave] = sm; }
        __syncthreads();
        if (tid == 0) {
            float tss = rss[0] + rss[1] + rss[2] + rss[3];
            float tsm = rsm[0] + rsm[1] + rsm[2] + rsm[3];
            float r = 1.0f / fmaxf(sqrtf(tss), 1e-12f);
            rn[blk] = r;
            s[blk] = tsm * r;
        }
        // zero u (18432 floats) + counters (384 words) = 18816
        int gid = blk * 256 + tid;
        if (gid < 3 * BB * TT * HH + 3 * BB * CTRS) uz[gid] = 0.f;
    } else {
        const int g = blk - BB * TT;
        const int b = g >> 6;
        const int j0 = (g & 63) * JT;

        __shared__ float xs[JT][33];
        __shared__ float Ws[32][32];
        for (int i = tid; i < 1024; i += 256) Ws[i >> 5][i & 31] = W0[i];
        {
            const float4* eb = (const float4*)(Edge + ((size_t)b * NN + j0) * HH);
#pragma unroll
            for (int k = 0; k < 2; ++k) {
                int i = tid + k * 256;
                float4 v = eb[i];
                int r0 = i >> 3, c0 = (i & 7) * 4;
                xs[r0][c0] = v.x; xs[r0][c0 + 1] = v.y; xs[r0][c0 + 2] = v.z; xs[r0][c0 + 3] = v.w;
            }
        }
        __syncthreads();
        const int r = tid >> 2;
        const int h0 = (tid & 3) * 8;
        float zr[8];
#pragma unroll
        for (int hh = 0; hh < 8; ++hh) {
            float acc = 0.f;
#pragma unroll
            for (int e = 0; e < 32; ++e) acc += xs[r][e] * Ws[e][h0 + hh];
            zr[hh] = acc;
        }
        float* zb = z0raw + ((size_t)b * NN + j0 + r) * HH + h0;
        ((float4*)zb)[0] = make_float4(zr[0], zr[1], zr[2], zr[3]);
        ((float4*)zb)[1] = make_float4(zr[4], zr[5], zr[6], zr[7]);
    }
}

// ---------------- K2: persistent 3-layer kernel with per-batch barriers ----------------
// Barrier uses RELAXED memory-side atomics only. Correctness argument:
//  - each block's u-atomicAdds are drained by the compiler's s_waitcnt vmcnt(0)
//    before the s_barrier that precedes the signal (memory-side, never cached);
//  - counter fetch_add / spin load are RELAXED agent-scope atomics -> bypass
//    L1/L2, no wbL2/invL2 cache maintenance (that was R6's 15-20us/barrier);
//  - u is only ever accessed via atomics, so no stale cache lines can exist.
__global__ __launch_bounds__(256) void k_mega(const float* __restrict__ Flow,
                                              const float* __restrict__ z0raw,
                                              const float* __restrict__ rn,
                                              const float* __restrict__ s,
                                              const float* __restrict__ W1,
                                              const float* __restrict__ W2,
                                              const float* __restrict__ b0,
                                              const float* __restrict__ b1,
                                              const float* __restrict__ b2,
                                              float* __restrict__ u,
                                              unsigned* __restrict__ ctr,
                                              float* __restrict__ out) {
    const int blk = blockIdx.x;
    const int b = blk >> 6;
    const int j0 = (blk & 63) * JT;
    const int tid = threadIdx.x;

    __shared__ float xns[TT][JT];
    __shared__ float zs[JT][33];
    __shared__ float xs[JT][33];
    __shared__ float W1s[32][32];
    __shared__ float W2s[32][32];
    __shared__ float us[TT][32];
    __shared__ float sS[TT];
    __shared__ float b0s[32], b1s[32], b2s[32];

    if (tid < TT) sS[tid] = s[b * TT + tid];
    if (tid < 32) { b0s[tid] = b0[tid]; b1s[tid] = b1[tid]; b2s[tid] = b2[tid]; }
    for (int i = tid; i < 1024; i += 256) { W1s[i >> 5][i & 31] = W1[i]; W2s[i >> 5][i & 31] = W2[i]; }
    {
        const float4* zt = (const float4*)(z0raw + ((size_t)b * NN + j0) * HH);
#pragma unroll
        for (int k = 0; k < 2; ++k) {
            int i = tid + k * 256;
            float4 v = zt[i];
            int r0 = i >> 3, c0 = (i & 7) * 4;
            zs[r0][c0] = v.x; zs[r0][c0 + 1] = v.y; zs[r0][c0 + 2] = v.z; zs[r0][c0 + 3] = v.w;
        }
    }
    {
        const float* flb = Flow + (size_t)b * TT * NN + j0;
        for (int i = tid; i < TT * (JT / 4); i += 256) {
            int t = i >> 4, c0 = (i & 15) * 4;
            float4 v = ((const float4*)(flb + t * NN))[i & 15];
            float rt = rn[b * TT + t];
            xns[t][c0] = v.x * rt; xns[t][c0 + 1] = v.y * rt;
            xns[t][c0 + 2] = v.z * rt; xns[t][c0 + 3] = v.w * rt;
        }
    }
    __syncthreads();

    const int r = tid >> 2;
    const int h0 = (tid & 3) * 8;
    float deg = 1.0f;
#pragma unroll
    for (int t = 0; t < TT; ++t) deg += xns[t][r] * sS[t];
    const float di = (deg > 0.f) ? rsqrtf(deg) : 0.f;
#pragma unroll
    for (int hh = 0; hh < 8; ++hh) zs[r][h0 + hh] *= di;   // zs = di * z0raw
    __syncthreads();

    float* u0 = u + b * UPB;
    float* u1 = u0 + BB * UPB;
    float* u2 = u1 + BB * UPB;

#define U_PART(dst)                                                        \
    {                                                                      \
        _Pragma("unroll")                                                  \
        for (int k = 0; k < 3; ++k) {                                      \
            int p = tid + k * 256;                                         \
            int t = p >> 5, h = p & 31;                                    \
            float acc = 0.f;                                               \
            _Pragma("unroll 8")                                            \
            for (int rr = 0; rr < JT; ++rr) acc += xns[t][rr] * zs[rr][h]; \
            atomicAdd(&(dst)[t * HH + h], acc);                            \
        }                                                                  \
    }

#define BAR(phase)                                                                  \
    {                                                                               \
        __syncthreads(); /* compiler drains vmcnt before s_barrier */               \
        if (tid == 0) {                                                             \
            unsigned* c = ctr + ((phase) * BB + b) * CTRS;                          \
            __hip_atomic_fetch_add(c, 1u, __ATOMIC_RELAXED, __HIP_MEMORY_SCOPE_AGENT); \
            while (__hip_atomic_load(c, __ATOMIC_RELAXED, __HIP_MEMORY_SCOPE_AGENT) < 64u) \
                __builtin_amdgcn_s_sleep(4);                                        \
        }                                                                           \
        __syncthreads();                                                            \
    }

#define LOAD_US(src)                                                                \
    {                                                                               \
        _Pragma("unroll")                                                           \
        for (int k = 0; k < 3; ++k) {                                               \
            int p = tid + k * 256;                                                  \
            us[p >> 5][p & 31] = __hip_atomic_load(&(src)[p], __ATOMIC_RELAXED,     \
                                                   __HIP_MEMORY_SCOPE_AGENT);       \
        }                                                                           \
        __syncthreads();                                                            \
    }

    // ---- layer 0 reduction ----
    U_PART(u0);
    BAR(0);
    LOAD_US(u0);

    // ---- layer 1 ----
#pragma unroll
    for (int hh = 0; hh < 8; ++hh) {
        int h = h0 + hh;
        float acc = 0.f;
#pragma unroll
        for (int t = 0; t < TT; ++t) acc += xns[t][r] * us[t][h];
        xs[r][h] = fmaxf(di * (acc + zs[r][h]) + b0s[h], 0.f);
    }
    // threads 4r..4r+3 (same wave64) wrote xs[r][0..31]: program-order LDS
    // visibility within a wave (validated R1/R2/R4/R5/R6)
#pragma unroll
    for (int hh = 0; hh < 8; ++hh) {
        float acc = 0.f;
#pragma unroll
        for (int e = 0; e < 32; ++e) acc += xs[r][e] * W1s[e][h0 + hh];
        zs[r][h0 + hh] = di * acc;
    }
    __syncthreads();
    U_PART(u1);
    BAR(1);
    LOAD_US(u1);

    // ---- layer 2 ----
#pragma unroll
    for (int hh = 0; hh < 8; ++hh) {
        int h = h0 + hh;
        float acc = 0.f;
#pragma unroll
        for (int t = 0; t < TT; ++t) acc += xns[t][r] * us[t][h];
        xs[r][h] = fmaxf(di * (acc + zs[r][h]) + b1s[h], 0.f);
    }
#pragma unroll
    for (int hh = 0; hh < 8; ++hh) {
        float acc = 0.f;
#pragma unroll
        for (int e = 0; e < 32; ++e) acc += xs[r][e] * W2s[e][h0 + hh];
        zs[r][h0 + hh] = di * acc;
    }
    __syncthreads();
    U_PART(u2);
    BAR(2);
    LOAD_US(u2);

    // ---- final B -> out ----
    float o[8];
#pragma unroll
    for (int hh = 0; hh < 8; ++hh) {
        int h = h0 + hh;
        float acc = 0.f;
#pragma unroll
        for (int t = 0; t < TT; ++t) acc += xns[t][r] * us[t][h];
        o[hh] = fmaxf(di * (acc + zs[r][h]) + b2s[h], 0.f);
    }
    float* orow = out + ((size_t)b * NN + j0 + r) * HH + h0;
    ((float4*)orow)[0] = make_float4(o[0], o[1], o[2], o[3]);
    ((float4*)orow)[1] = make_float4(o[4], o[5], o[6], o[7]);

#undef U_PART
#undef BAR
#undef LOAD_US
}

extern "C" void kernel_launch(void* const* d_in, const int* in_sizes, int n_in,
                              void* d_out, int out_size, void* d_ws, size_t ws_size,
                              hipStream_t stream) {
    const float* Flow = (const float*)d_in[0];
    const float* Edge = (const float*)d_in[1];
    const float* W0 = (const float*)d_in[2];
    const float* b0 = (const float*)d_in[3];
    const float* W1 = (const float*)d_in[4];
    const float* b1 = (const float*)d_in[5];
    const float* W2 = (const float*)d_in[6];
    const float* b2 = (const float*)d_in[7];
    float* out = (float*)d_out;

    float* ws = (float*)d_ws;
    float* rn    = ws;                                  // B*T
    float* s     = rn + BB * TT;                        // B*T
    float* z0raw = s + BB * TT;                         // B*N*H
    float* u     = z0raw + (size_t)BB * NN * HH;        // 3*B*T*H
    unsigned* ctr = (unsigned*)(u + 3 * BB * UPB);      // 3*B*CTRS words

    k_phase1<<<dim3(BB * TT + 512), 256, 0, stream>>>(Flow, Edge, W0, rn, s, u, z0raw);
    k_mega<<<dim3(512), 256, 0, stream>>>(Flow, z0raw, rn, s, W1, W2, b0, b1, b2,
                                          u, ctr, out);
}